// Round 5
// baseline (275.665 us; speedup 1.0000x reference)
//
#include <hip/hip_runtime.h>
#include <stdint.h>

// Problem constants
#define E_DIM 256
#define HEADS 8
#define NQ 49
#define S_TOT 196      // 14*14
#define NROIS 512
#define FH 152
#define FW 256
#define HW_TOT (FH*FW) // 38912

typedef unsigned short u16;
typedef short bf16x8 __attribute__((ext_vector_type(8)));
typedef float f32x4 __attribute__((ext_vector_type(4)));
typedef unsigned short us8 __attribute__((ext_vector_type(8)));

#define MFMA(a,b,c) __builtin_amdgcn_mfma_f32_16x16x32_bf16((a),(b),(c),0,0,0)

__device__ __forceinline__ u16 f2bf(float f) {
  union { float f; uint32_t u; } v; v.f = f;
  uint32_t u = v.u;
  return (u16)((u + 0x7FFFu + ((u >> 16) & 1u)) >> 16);
}
__device__ __forceinline__ float bf2f(u16 h) {
  union { uint32_t u; float f; } v; v.u = ((uint32_t)h) << 16;
  return v.f;
}
__device__ __forceinline__ bf16x8 ld_frag(const u16* p) {   // 2x ds_read_b64
  union { uint2 d[2]; bf16x8 v; } t;
  t.d[0] = *(const uint2*)(p);
  t.d[1] = *(const uint2*)(p + 4);
  return t.v;
}
__device__ __forceinline__ bf16x8 ld_frag_g(const u16* p) { // 16B global
  union { uint4 d; bf16x8 v; } t;
  t.d = *(const uint4*)(p);
  return t.v;
}
__device__ __forceinline__ ushort4 pack4(float a, float b, float c, float d) {
  ushort4 r; r.x = f2bf(a); r.y = f2bf(b); r.z = f2bf(c); r.w = f2bf(d); return r;
}

// ---------------- K0: convert weights + qs (tiny) ----------------
// blocks [0,256): weight convert; [256,264): qs
__global__ __launch_bounds__(256) void prep_all(
    const float* __restrict__ ipw, const float* __restrict__ opw,
    const float* __restrict__ ipb, const float* __restrict__ cq,
    u16* __restrict__ Wk, u16* __restrict__ Wv, u16* __restrict__ Wo,
    u16* __restrict__ qs)
{
  const int b = blockIdx.x;
  const int t = threadIdx.x;
  if (b < 256) {
    int i = (b << 8) + t;
    Wk[i] = f2bf(ipw[65536 + i]);
    Wv[i] = f2bf(ipw[131072 + i]);
    Wo[i] = f2bf(opw[i]);
  } else {
    int h = b - 256;
    for (int r = 0; r < 8; ++r) {
      int o = t + 256*r;
      int qq = o >> 5, d = o & 31;
      float acc = 0.f;
      if (qq < NQ) {
        acc = ipb[h*32 + d];
        const float4* wr = (const float4*)(ipw + (size_t)(h*32 + d)*256);
        const float4* cr = (const float4*)(cq + (size_t)qq*256);
        float s = 0.f;
        for (int e = 0; e < 64; ++e) {
          float4 a = cr[e], bb = wr[e];
          s += a.x*bb.x + a.y*bb.y + a.z*bb.z + a.w*bb.w;
        }
        acc = (acc + s) * 0.17677669529663687f;   // 1/sqrt(32)
      }
      qs[h*2048 + o] = f2bf(acc);
    }
  }
}

// ---------------- K1: fK/fV = features^T @ W^T, HEAD-MAJOR output [8][HW][32] ----------------
// Self-staged A (f32 -> bf16 transpose in LDS); LDS-retiled fully-coalesced stores.
#define AT_ST 264
#define CT_ST 276
__global__ __launch_bounds__(512, 2) void proj_kv(
    const float* __restrict__ f, const u16* __restrict__ Wk, const u16* __restrict__ Wv,
    u16* __restrict__ fK, u16* __restrict__ fV)
{
  __shared__ union __align__(16) {
    u16 At[64][AT_ST];      // 33,792 B  A-tile [m(hw)][k(ch)] bf16
    u16 ct[2][64][CT_ST];   // 70,656 B  C staging [map][m][n]
  } sm;
  const int m0 = blockIdx.x << 6;
  const int t = threadIdx.x;
  const int lane = t & 63;
  const int w = t >> 6;
  const int g = lane >> 4, l15 = lane & 15;
  const int map = w >> 2;
  const u16* W = map ? Wv : Wk;
  const int nq = (w & 3) << 6;

  // stage + transpose + convert: At[hw][c] = bf16(f[c][m0+hw])
#pragma unroll
  for (int it = 0; it < 8; ++it) {
    int c = (t >> 4) + (it << 5);
    int hwq = (t & 15) << 2;
    float4 v = *(const float4*)(f + (size_t)c*HW_TOT + m0 + hwq);
    sm.At[hwq][c]     = f2bf(v.x);
    sm.At[hwq + 1][c] = f2bf(v.y);
    sm.At[hwq + 2][c] = f2bf(v.z);
    sm.At[hwq + 3][c] = f2bf(v.w);
  }
  __syncthreads();

  f32x4 acc[4][4];
#pragma unroll
  for (int mf = 0; mf < 4; ++mf)
#pragma unroll
    for (int nt = 0; nt < 4; ++nt) acc[mf][nt] = (f32x4){0.f,0.f,0.f,0.f};

  for (int kt = 0; kt < 8; ++kt) {
    bf16x8 a[4], bb[4];
#pragma unroll
    for (int mf = 0; mf < 4; ++mf)
      a[mf] = ld_frag(&sm.At[(mf << 4) + l15][(kt << 5) + (g << 3)]);
#pragma unroll
    for (int nt = 0; nt < 4; ++nt)
      bb[nt] = ld_frag_g(W + (size_t)(nq + (nt << 4) + l15)*256 + (kt << 5) + (g << 3));
#pragma unroll
    for (int mf = 0; mf < 4; ++mf)
#pragma unroll
      for (int nt = 0; nt < 4; ++nt)
        acc[mf][nt] = MFMA(a[mf], bb[nt], acc[mf][nt]);
  }
  __syncthreads();   // At dead
#pragma unroll
  for (int mf = 0; mf < 4; ++mf)
#pragma unroll
    for (int nt = 0; nt < 4; ++nt)
#pragma unroll
      for (int i = 0; i < 4; ++i)
        sm.ct[map][(mf << 4) + (g << 2) + i][nq + (nt << 4) + l15] = f2bf(acc[mf][nt][i]);
  __syncthreads();
  // head-major store: wave w -> (map2 = w>>2, heads 2*(w&3)+{0,1}); 1KB contiguous/inst
  const int map2 = w >> 2;
  u16* dstmap = map2 ? fV : fK;
#pragma unroll
  for (int hh = 0; hh < 2; ++hh) {
    int hsel = ((w & 3) << 1) + hh;
#pragma unroll
    for (int mi = 0; mi < 4; ++mi) {
      int m = (lane >> 2) + (mi << 4);
      int chunk = lane & 3;
      bf16x8 val = ld_frag(&sm.ct[map2][m][(hsel << 5) + (chunk << 3)]);
      u16* dst = dstmap + (((size_t)hsel*HW_TOT + m0 + m) << 5) + (chunk << 3);
      *(us8*)dst = *(const us8*)&val;
    }
  }
}

// ---------------- K2: main fused kernel: 512 thr/ROI, window-stencil sampling ----------------
// ROI side is exactly 224 -> bw=bh=1 -> all 196 samples share ONE bilinear weight
// quad and lie on an integer-aligned 15x15 map window.
#define AK_ST 228     // attn rows; windows alias this region
#define KS_ST 36
#define VT_ST 228
#define OR_ST 36
#define AS_ST 260
#define PS_ST 260
struct SMemA {
  u16 attn[64][AK_ST];    // 29,184 B  attn [q][s]; head windows alias (14,400 u16)
  u16 ksmp[208][KS_ST];   // 14,976 B  k_h [s][32]
  u16 vT[32][VT_ST];      // 14,592 B  v_h^T [d][s]
  u16 ore[64][OR_ST];     //  4,608 B
};                         // 63,360 B
struct SMemC {
  u16 ast[NQ][AS_ST];     // 25,480 B
  u16 pos[NQ][PS_ST];     // 25,480 B
  u16 pwin[15*15*64];     // 28,800 B  f-window quarter [r][c][64ch]
};                         // 79,760 B
union __align__(16) SMem { SMemA a; SMemC c; };

__global__ __launch_bounds__(512, 2) void fused_roi_attn(
    const float* __restrict__ rois,
    const float* __restrict__ balance_p,
    const float* __restrict__ bv,       // in_proj_bias + 512
    const float* __restrict__ bout,
    const float* __restrict__ f,        // raw features [256][152][256] f32
    const u16*  __restrict__ fK,        // [8][HW][32] bf16 head-major
    const u16*  __restrict__ fV,
    const u16*  __restrict__ Woutbf,
    const u16*  __restrict__ qsPad,     // [8][64][32]
    float* __restrict__ out)            // [512][256][49]
{
  __shared__ SMem sm;
  u16* win = &sm.a.attn[0][0];          // [2 maps][15r][15c][32ch] = 14,400 u16
  const int tid = threadIdx.x;
  const int lane = tid & 63;
  const int w = tid >> 6;
  const int v = w >> 2;
  const int w2 = w & 3;
  const int g = lane >> 4;
  const int l15 = lane & 15;
  const int n = blockIdx.x;

  // ---- ROI -> integer window origin + one bilinear weight quad ----
  float X = rois[n*5 + 1] * 0.0625f;
  float Y = rois[n*5 + 2] * 0.0625f;
  float fx0 = floorf(X), fy0 = floorf(Y);
  const int ix0 = (int)fx0, iy0 = (int)fy0;
  const float lx = X - fx0, ly = Y - fy0;
  const float hx = 1.0f - lx, hy = 1.0f - ly;
  const float w00 = hy*hx, w01 = hy*lx, w10 = ly*hx, w11 = ly*lx;

  // zero vT pad cols once (cols 196..227; stencil writes only <196)
  for (int i = tid; i < 32*32; i += 512) sm.a.vT[i >> 5][196 + (i & 31)] = 0;

  float bal;
  { float bp = balance_p[0]; bal = fminf(fmaxf(bp*(1.0f/6.0f) + 0.5f, 0.0f), 1.0f); }

  f32x4 attacc[8];
#pragma unroll
  for (int i = 0; i < 8; ++i) attacc[i] = (f32x4){0.f,0.f,0.f,0.f};

  for (int h = 0; h < HEADS; ++h) {
    __syncthreads();   // T: prev-head attn/vT/ore reads done

    // ---- stage K/V windows (dense, coalesced; row = 960B contiguous) ----
#pragma unroll
    for (int it = 0; it < 4; ++it) {
      int slot = tid + (it << 9);
      if (slot < 1800) {
        int map = slot >= 900;
        int ms = map ? slot - 900 : slot;
        int r = ms / 60;
        int ch = ms - r*60;
        int p = ch >> 2, c4 = ch & 3;
        int yg = min(iy0 + r, FH - 1);
        int xg = min(ix0 + p, FW - 1);
        const u16* src = (map ? fV : fK)
            + (((size_t)h*HW_TOT + yg*FW + xg) << 5) + (c4 << 3);
        *(us8*)(win + map*7200 + (r*15 + p)*32 + (c4 << 3)) = *(const us8*)src;
      }
    }
    __syncthreads();   // S: windows ready

    // ---- 2x2 uniform stencil: ksmp[s][32], vT[d][s] ----
#pragma unroll
    for (int it = 0; it < 2; ++it) {
      int item = tid + (it << 9);
      if (item < 784) {
        int s = item >> 2;
        int c8 = (item & 3) << 3;
        int gy = s / 14, gx = s - gy*14;
        const u16* kp = win + (gy*15 + gx)*32 + c8;
        us8 a00 = *(const us8*)(kp);
        us8 a01 = *(const us8*)(kp + 32);
        us8 a10 = *(const us8*)(kp + 480);
        us8 a11 = *(const us8*)(kp + 512);
        const u16* vp = kp + 7200;
        us8 b00 = *(const us8*)(vp);
        us8 b01 = *(const us8*)(vp + 32);
        us8 b10 = *(const us8*)(vp + 480);
        us8 b11 = *(const us8*)(vp + 512);
        float kk[8], vv[8];
#pragma unroll
        for (int c = 0; c < 8; ++c) {
          kk[c] = w00*bf2f(a00[c]) + w01*bf2f(a01[c]) + w10*bf2f(a10[c]) + w11*bf2f(a11[c]);
          vv[c] = w00*bf2f(b00[c]) + w01*bf2f(b01[c]) + w10*bf2f(b10[c]) + w11*bf2f(b11[c]);
        }
        u16* krow = &sm.a.ksmp[s][c8];
        *(ushort4*)(krow)     = pack4(kk[0], kk[1], kk[2], kk[3]);
        *(ushort4*)(krow + 4) = pack4(kk[4], kk[5], kk[6], kk[7]);
#pragma unroll
        for (int j = 0; j < 8; ++j) sm.a.vT[c8 + j][s] = f2bf(vv[j]);
      }
    }
    __syncthreads();   // U: ksmp/vT ready; windows dead (attn region writable)

    if (v == 0) {
      // ---- logits[q=16w2+4g+i][s=16nt+l15] ----
      bf16x8 aq = ld_frag_g(qsPad + (size_t)((h << 6) + (w2 << 4) + l15)*32 + (g << 3));
      f32x4 lac[13];
#pragma unroll
      for (int nt = 0; nt < 13; ++nt) {
        bf16x8 bk = ld_frag(&sm.a.ksmp[(nt << 4) + l15][g << 3]);
        f32x4 z = (f32x4){0.f,0.f,0.f,0.f};
        lac[nt] = MFMA(aq, bk, z);
      }
      if (l15 >= 4) {
#pragma unroll
        for (int i = 0; i < 4; ++i) lac[12][i] = -1e30f;
      }
      // ---- softmax over s ----
      float srow[4];
#pragma unroll
      for (int i = 0; i < 4; ++i) {
        float m = lac[0][i];
#pragma unroll
        for (int nt = 1; nt < 13; ++nt) m = fmaxf(m, lac[nt][i]);
#pragma unroll
        for (int off = 1; off < 16; off <<= 1) m = fmaxf(m, __shfl_xor(m, off, 64));
        float sumv = 0.f;
#pragma unroll
        for (int nt = 0; nt < 13; ++nt) {
          float p = __expf(lac[nt][i] - m);
          lac[nt][i] = p; sumv += p;
        }
#pragma unroll
        for (int off = 1; off < 16; off <<= 1) sumv += __shfl_xor(sumv, off, 64);
        srow[i] = 1.0f / sumv;
      }
#pragma unroll
      for (int nt = 0; nt < 13; ++nt)
#pragma unroll
        for (int i = 0; i < 4; ++i)
          sm.a.attn[(w2 << 4) + (g << 2) + i][(nt << 4) + l15] = f2bf(lac[nt][i]*srow[i]);
    } else {
      // zero attn pad cols 208..223 (clobbered by window staging each head)
      int t2 = tid - 256;
      *(ushort4*)(&sm.a.attn[t2 >> 2][208 + ((t2 & 3) << 2)]) = (ushort4){0,0,0,0};
    }
    __syncthreads();   // P: attn ready

    // ---- PV (duplicated across v; cheap pipes) ----
    f32x4 o0 = (f32x4){0.f,0.f,0.f,0.f}, o1 = (f32x4){0.f,0.f,0.f,0.f};
#pragma unroll
    for (int kt = 0; kt < 7; ++kt) {
      bf16x8 ap = ld_frag(&sm.a.attn[(w2 << 4) + l15][(kt << 5) + (g << 3)]);
      bf16x8 b0 = ld_frag(&sm.a.vT[l15][(kt << 5) + (g << 3)]);
      bf16x8 b1 = ld_frag(&sm.a.vT[16 + l15][(kt << 5) + (g << 3)]);
      o0 = MFMA(ap, b0, o0);
      o1 = MFMA(ap, b1, o1);
    }
    float bv0 = bv[(h << 5) + l15];
    float bv1 = bv[(h << 5) + 16 + l15];
#pragma unroll
    for (int i = 0; i < 4; ++i) {
      sm.a.ore[(w2 << 4) + (g << 2) + i][l15]      = f2bf(o0[i] + bv0);
      sm.a.ore[(w2 << 4) + (g << 2) + i][16 + l15] = f2bf(o1[i] + bv1);
    }
    // ---- out-projection (split by v; reads rows this wave wrote) ----
    bf16x8 ao = ld_frag(&sm.a.ore[(w2 << 4) + l15][g << 3]);
#pragma unroll
    for (int j = 0; j < 8; ++j) {
      int nt = (v << 3) + j;
      bf16x8 bo = ld_frag_g(Woutbf + (size_t)((nt << 4) + l15)*256 + (h << 5) + (g << 3));
      attacc[j] = MFMA(ao, bo, attacc[j]);
    }
  } // heads

  // ---- Phase C ----
  __syncthreads();   // all A-region reads done
#pragma unroll
  for (int j = 0; j < 8; ++j) {
    int nt = (v << 3) + j;
    float bo = bout[(nt << 4) + l15];
#pragma unroll
    for (int i = 0; i < 4; ++i) {
      int r = (w2 << 4) + (g << 2) + i;
      if (r < NQ) sm.c.ast[r][(nt << 4) + l15] = f2bf(attacc[j][i] + bo);
    }
  }
  // pos via 3x3 separable stencil [hy,1,ly](x)[hx,1,lx]/4 on raw f32 windows, 4 quarters
  const int xe = FW - 1 - ix0;          // col-14 clamp index (13 or 14)
  for (int qt = 0; qt < 4; ++qt) {
    __syncthreads();   // prev quarter's pwin reads done
#pragma unroll
    for (int it = 0; it < 2; ++it) {
      int unit = tid + (it << 9);
      if (unit < 960) {
        int ch = unit / 15, r = unit - 15*(unit/15);
        int yg = min(iy0 + r, FH - 1);
        const float* src = f + ((size_t)((qt << 6) + ch))*HW_TOT + yg*FW + ix0;
        u16* d = sm.c.pwin + (r*15)*64 + ch;
        float4 v0 = *(const float4*)(src);
        float4 v1 = *(const float4*)(src + 4);
        float4 v2 = *(const float4*)(src + 8);
        float2 v3 = *(const float2*)(src + 12);
        float  v4 = src[min(14, xe)];
        d[0]      = f2bf(v0.x); d[64]     = f2bf(v0.y); d[128]    = f2bf(v0.z); d[192]  = f2bf(v0.w);
        d[256]    = f2bf(v1.x); d[320]    = f2bf(v1.y); d[384]    = f2bf(v1.z); d[448]  = f2bf(v1.w);
        d[512]    = f2bf(v2.x); d[576]    = f2bf(v2.y); d[640]    = f2bf(v2.z); d[704]  = f2bf(v2.w);
        d[768]    = f2bf(v3.x); d[832]    = f2bf(v3.y); d[896]    = f2bf(v4);
      }
    }
    __syncthreads();
    float wy[3] = {hy, 1.0f, ly};
    float wx[3] = {hx, 1.0f, lx};
#pragma unroll
    for (int it = 0; it < 2; ++it) {
      int item = tid + (it << 9);
      if (item < 784) {
        int q = item >> 4, c4 = item & 15;
        int oy = q / 7, ox = q - oy*7;
        float a0 = 0.f, a1 = 0.f, a2 = 0.f, a3 = 0.f;
#pragma unroll
        for (int j = 0; j < 3; ++j) {
          const u16* rp = sm.c.pwin + (((oy << 1) + j)*15 + (ox << 1))*64 + (c4 << 2);
#pragma unroll
          for (int i = 0; i < 3; ++i) {
            ushort4 tv = *(const ushort4*)(rp + (i << 6));
            float wji = wy[j]*wx[i];
            a0 += wji*bf2f(tv.x); a1 += wji*bf2f(tv.y);
            a2 += wji*bf2f(tv.z); a3 += wji*bf2f(tv.w);
          }
        }
        *(ushort4*)(&sm.c.pos[q][(qt << 6) + (c4 << 2)]) =
            pack4(0.25f*a0, 0.25f*a1, 0.25f*a2, 0.25f*a3);
      }
    }
  }
  __syncthreads();
  float ibal = 1.0f - bal;
  float* outp = out + (size_t)n*(E_DIM*NQ);
  for (int j = 0; j < 25; ++j) {
    int idx = (j << 9) + tid;
    if (idx < E_DIM*NQ) {
      int eo = idx/49;
      int q  = idx - eo*49;
      outp[idx] = bal*bf2f(sm.c.pos[q][eo]) + ibal*bf2f(sm.c.ast[q][eo]);
    }
  }
}

// ---------------- launcher ----------------
// ws: fK | fV (19,922,944 B each) | Wk | Wv | Wo (131,072 each) | qs 32,768
extern "C" void kernel_launch(void* const* d_in, const int* in_sizes, int n_in,
                              void* d_out, int out_size, void* d_ws, size_t ws_size,
                              hipStream_t stream) {
  const float* features = (const float*)d_in[0];
  const float* rois     = (const float*)d_in[1];
  const float* cq       = (const float*)d_in[2];
  const float* ipw      = (const float*)d_in[3];
  const float* ipb      = (const float*)d_in[4];
  const float* opw      = (const float*)d_in[5];
  const float* opb      = (const float*)d_in[6];
  const float* balp     = (const float*)d_in[7];
  float* out = (float*)d_out;

  char* ws = (char*)d_ws;
  const size_t FMB = (size_t)HW_TOT*256*2;   // 19,922,944
  u16* fK = (u16*)ws;
  u16* fV = (u16*)(ws + FMB);
  u16* Wk = (u16*)(ws + 2*FMB);
  u16* Wv = Wk + 65536;
  u16* Wo = Wv + 65536;
  u16* qs = Wo + 65536;

  hipLaunchKernelGGL(prep_all, dim3(264), dim3(256), 0, stream,
                     ipw, opw, ipb, cq, Wk, Wv, Wo, qs);
  hipLaunchKernelGGL(proj_kv,  dim3(HW_TOT/64), dim3(512), 0, stream,
                     features, Wk, Wv, fK, fV);
  hipLaunchKernelGGL(fused_roi_attn, dim3(NROIS), dim3(512), 0, stream,
                     rois, balp, ipb + 512, opb, features, fK, fV, Wo, qs, out);
}

// Round 6
// 226.210 us; speedup vs baseline: 1.2186x; 1.2186x over previous
//
#include <hip/hip_runtime.h>
#include <stdint.h>

// Problem constants
#define E_DIM 256
#define HEADS 8
#define NQ 49
#define S_TOT 196      // 14*14
#define NROIS 512
#define FH 152
#define FW 256
#define HW_TOT (FH*FW) // 38912

typedef unsigned short u16;
typedef short bf16x8 __attribute__((ext_vector_type(8)));
typedef float f32x4 __attribute__((ext_vector_type(4)));
typedef unsigned short us8 __attribute__((ext_vector_type(8)));

#define MFMA(a,b,c) __builtin_amdgcn_mfma_f32_16x16x32_bf16((a),(b),(c),0,0,0)

__device__ __forceinline__ u16 f2bf(float f) {
  union { float f; uint32_t u; } v; v.f = f;
  uint32_t u = v.u;
  return (u16)((u + 0x7FFFu + ((u >> 16) & 1u)) >> 16);
}
__device__ __forceinline__ float bf2f(u16 h) {
  union { uint32_t u; float f; } v; v.u = ((uint32_t)h) << 16;
  return v.f;
}
// packed f32x2 -> bf16x2 (RNE), single HW instruction
__device__ __forceinline__ uint32_t cvtpk(float lo, float hi) {
  uint32_t r;
  asm("v_cvt_pk_bf16_f32 %0, %1, %2" : "=v"(r) : "v"(lo), "v"(hi));
  return r;
}
__device__ __forceinline__ bf16x8 ld_frag(const u16* p) {   // 2x ds_read_b64
  union { uint2 d[2]; bf16x8 v; } t;
  t.d[0] = *(const uint2*)(p);
  t.d[1] = *(const uint2*)(p + 4);
  return t.v;
}
__device__ __forceinline__ bf16x8 ld_frag_g(const u16* p) { // 16B global
  union { uint4 d; bf16x8 v; } t;
  t.d = *(const uint4*)(p);
  return t.v;
}

// ---------------- K0: convert weights + qs (tiny) ----------------
__global__ __launch_bounds__(256) void prep_small(
    const float* __restrict__ ipw, const float* __restrict__ opw,
    const float* __restrict__ ipb, const float* __restrict__ cq,
    u16* __restrict__ Wk, u16* __restrict__ Wv, u16* __restrict__ Wo,
    u16* __restrict__ qs)
{
  const int b = blockIdx.x;
  const int t = threadIdx.x;
  if (b < 256) {
    int i = (b << 8) + t;
    Wk[i] = f2bf(ipw[65536 + i]);
    Wv[i] = f2bf(ipw[131072 + i]);
    Wo[i] = f2bf(opw[i]);
  } else {
    int h = b - 256;
    for (int r = 0; r < 8; ++r) {
      int o = t + 256*r;
      int qq = o >> 5, d = o & 31;
      float acc = 0.f;
      if (qq < NQ) {
        acc = ipb[h*32 + d];
        const float4* wr = (const float4*)(ipw + (size_t)(h*32 + d)*256);
        const float4* cr = (const float4*)(cq + (size_t)qq*256);
        float s = 0.f;
        for (int e = 0; e < 64; ++e) {
          float4 a = cr[e], bb = wr[e];
          s += a.x*bb.x + a.y*bb.y + a.z*bb.z + a.w*bb.w;
        }
        acc = (acc + s) * 0.17677669529663687f;   // 1/sqrt(32)
      }
      qs[h*2048 + o] = f2bf(acc);
    }
  }
}

// ---------------- K1: fT (bf16 transpose) + fK/fV = f^T @ W^T head-major ----------------
// One pass over features: stage At[64 hw][256 ch] bf16 in LDS, emit fT rows,
// GEMM from LDS, stage C in LDS, coalesced head-major stores [8][HW][32].
#define AT_ST 264
#define CT_ST 276
__global__ __launch_bounds__(512, 2) void proj_kv(
    const float* __restrict__ f, const u16* __restrict__ Wk, const u16* __restrict__ Wv,
    u16* __restrict__ fT, u16* __restrict__ fK, u16* __restrict__ fV)
{
  __shared__ union __align__(16) {
    u16 At[64][AT_ST];      // 33,792 B
    u16 ct[2][64][CT_ST];   // 70,656 B
  } sm;
  const int m0 = blockIdx.x << 6;
  const int t = threadIdx.x;
  const int lane = t & 63;
  const int w = t >> 6;
  const int g = lane >> 4, l15 = lane & 15;
  const int map = w >> 2;
  const u16* W = map ? Wv : Wk;
  const int nq = (w & 3) << 6;

  // stage + transpose + convert: At[hw][c] = bf16(f[c][m0+hw])
#pragma unroll
  for (int it = 0; it < 8; ++it) {
    int c = (t >> 4) + (it << 5);
    int hwq = (t & 15) << 2;
    float4 v = *(const float4*)(f + (size_t)c*HW_TOT + m0 + hwq);
    sm.At[hwq][c]     = f2bf(v.x);
    sm.At[hwq + 1][c] = f2bf(v.y);
    sm.At[hwq + 2][c] = f2bf(v.z);
    sm.At[hwq + 3][c] = f2bf(v.w);
  }
  __syncthreads();

  // emit fT rows (coalesced 16B stores)
  {
    int r = t >> 3, c0 = (t & 7) << 5;
    u16* dst = fT + (size_t)(m0 + r)*256 + c0;
#pragma unroll
    for (int k = 0; k < 4; ++k)
      *(us8*)(dst + (k << 3)) = *(const us8*)(&sm.At[r][c0 + (k << 3)]);
  }

  f32x4 acc[4][4];
#pragma unroll
  for (int mf = 0; mf < 4; ++mf)
#pragma unroll
    for (int nt = 0; nt < 4; ++nt) acc[mf][nt] = (f32x4){0.f,0.f,0.f,0.f};

  for (int kt = 0; kt < 8; ++kt) {
    bf16x8 a[4], bb[4];
#pragma unroll
    for (int mf = 0; mf < 4; ++mf)
      a[mf] = ld_frag(&sm.At[(mf << 4) + l15][(kt << 5) + (g << 3)]);
#pragma unroll
    for (int nt = 0; nt < 4; ++nt)
      bb[nt] = ld_frag_g(W + (size_t)(nq + (nt << 4) + l15)*256 + (kt << 5) + (g << 3));
#pragma unroll
    for (int mf = 0; mf < 4; ++mf)
#pragma unroll
      for (int nt = 0; nt < 4; ++nt)
        acc[mf][nt] = MFMA(a[mf], bb[nt], acc[mf][nt]);
  }
  __syncthreads();   // At dead
#pragma unroll
  for (int mf = 0; mf < 4; ++mf)
#pragma unroll
    for (int nt = 0; nt < 4; ++nt)
#pragma unroll
      for (int i = 0; i < 4; ++i)
        sm.ct[map][(mf << 4) + (g << 2) + i][nq + (nt << 4) + l15] = f2bf(acc[mf][nt][i]);
  __syncthreads();
  // head-major store: wave w -> (map2 = w>>2, heads 2*(w&3)+{0,1}); 1KB contiguous/inst
  const int map2 = w >> 2;
  u16* dstmap = map2 ? fV : fK;
#pragma unroll
  for (int hh = 0; hh < 2; ++hh) {
    int hsel = ((w & 3) << 1) + hh;
#pragma unroll
    for (int mi = 0; mi < 4; ++mi) {
      int m = (lane >> 2) + (mi << 4);
      int chunk = lane & 3;
      bf16x8 val = ld_frag(&sm.ct[map2][m][(hsel << 5) + (chunk << 3)]);
      u16* dst = dstmap + (((size_t)hsel*HW_TOT + m0 + m) << 5) + (chunk << 3);
      *(us8*)dst = *(const us8*)&val;
    }
  }
}

// ---------------- K2: main fused kernel: 512 thr/ROI, uniform-quad gathers ----------------
// ROI side == 224 exactly -> bw=bh=1 -> one bilinear weight quad per ROI and the
// 14x14 sample grid is integer-aligned (verified R4). Gather K/V per head from
// head-major maps (64B line per pixel-slice); pos = 3x3 separable stencil on fT.
#define AT2_ST 228
#define KS_ST 36
#define VT_ST 228
#define OR_ST 36
#define AS_ST 260
#define PS_ST 260
struct SMemA {
  u16 attn[64][AT2_ST];   // 29,184 B  attn [q][s], cols 208..223 zeroed once
  u16 ksmp[208][KS_ST];   // 14,976 B  k_h [s][32] (rows 196..207 garbage, masked)
  u16 vT[32][VT_ST];      // 14,592 B  v_h^T [d][s], cols 196..227 zeroed once
  u16 ore[64][OR_ST];     //  4,608 B
};                         // 63,360 B
struct SMemC {
  u16 ast[NQ][AS_ST];     // 25,480 B
  u16 pos[NQ][PS_ST];     // 25,480 B
};
union __align__(16) SMem { SMemA a; SMemC c; };   // 63,360 B -> 2 blocks/CU

__global__ __launch_bounds__(512, 4) void fused_roi_attn(
    const float* __restrict__ rois,
    const float* __restrict__ balance_p,
    const float* __restrict__ bv,       // in_proj_bias + 512
    const float* __restrict__ bout,
    const u16*  __restrict__ fT,        // [HW][256] bf16
    const u16*  __restrict__ fK,        // [8][HW][32] bf16 head-major
    const u16*  __restrict__ fV,
    const u16*  __restrict__ Woutbf,
    const u16*  __restrict__ qsPad,     // [8][64][32]
    float* __restrict__ out)            // [512][256][49]
{
  __shared__ SMem sm;
  const int tid = threadIdx.x;
  const int lane = tid & 63;
  const int w = tid >> 6;
  const int v = w >> 2;
  const int w2 = w & 3;
  const int g = lane >> 4;
  const int l15 = lane & 15;
  const int n = blockIdx.x;

  // ---- ROI -> integer origin + one bilinear weight quad ----
  float X = rois[n*5 + 1] * 0.0625f;
  float Y = rois[n*5 + 2] * 0.0625f;
  float fx0 = floorf(X), fy0 = floorf(Y);
  const int ix0 = (int)fx0, iy0 = (int)fy0;
  const float lx = X - fx0, ly = Y - fy0;
  const float hx = 1.0f - lx, hy = 1.0f - ly;
  const float w00 = hy*hx, w01 = hy*lx, w10 = ly*hx, w11 = ly*lx;

  // per-thread gather slot (s, 16-ch half): head-invariant address parts
  const int s_slot = tid >> 1;
  const int hf = tid & 1;
  int pixoff = 0, dxs = 0, dys = 0;
  if (tid < 2*S_TOT) {
    int gy = s_slot/14, gx = s_slot - gy*14;
    int px = ix0 + gx, py = iy0 + gy;
    pixoff = (((py*FW) + px) << 5) + (hf << 4);
    dxs = (px + 1 < FW) ? 32 : 0;
    dys = (py + 1 < FH) ? (FW << 5) : 0;
  }
  const int hstep = HW_TOT << 5;

  // zero pads once (regions never clobbered during head loop)
  for (int i = tid; i < 32*32; i += 512) sm.a.vT[i >> 5][196 + (i & 31)] = 0;
  for (int i = tid; i < 64*16; i += 512) sm.a.attn[i >> 4][208 + (i & 15)] = 0;

  float bal;
  { float bp = balance_p[0]; bal = fminf(fmaxf(bp*(1.0f/6.0f) + 0.5f, 0.0f), 1.0f); }

  f32x4 attacc[8];
#pragma unroll
  for (int i = 0; i < 8; ++i) attacc[i] = (f32x4){0.f,0.f,0.f,0.f};

  for (int h = 0; h < HEADS; ++h) {
    __syncthreads();   // T: prior-head ksmp/vT reads done

    // ---- gather k_h -> ksmp[s][32], v_h -> vT[d][s] (one slot/thread) ----
    if (tid < 2*S_TOT) {
      const u16* pk = fK + h*hstep + pixoff;
      const u16* pv = fV + h*hstep + pixoff;
      int o11 = dxs + dys;
      us8 k00a = *(const us8*)(pk);       us8 k00b = *(const us8*)(pk + 8);
      us8 k01a = *(const us8*)(pk + dxs); us8 k01b = *(const us8*)(pk + dxs + 8);
      us8 k10a = *(const us8*)(pk + dys); us8 k10b = *(const us8*)(pk + dys + 8);
      us8 k11a = *(const us8*)(pk + o11); us8 k11b = *(const us8*)(pk + o11 + 8);
      us8 v00a = *(const us8*)(pv);       us8 v00b = *(const us8*)(pv + 8);
      us8 v01a = *(const us8*)(pv + dxs); us8 v01b = *(const us8*)(pv + dxs + 8);
      us8 v10a = *(const us8*)(pv + dys); us8 v10b = *(const us8*)(pv + dys + 8);
      us8 v11a = *(const us8*)(pv + o11); us8 v11b = *(const us8*)(pv + o11 + 8);
      float kk[16], vv[16];
#pragma unroll
      for (int c = 0; c < 8; ++c) {
        kk[c]   = w00*bf2f(k00a[c]) + w01*bf2f(k01a[c]) + w10*bf2f(k10a[c]) + w11*bf2f(k11a[c]);
        kk[c+8] = w00*bf2f(k00b[c]) + w01*bf2f(k01b[c]) + w10*bf2f(k10b[c]) + w11*bf2f(k11b[c]);
        vv[c]   = w00*bf2f(v00a[c]) + w01*bf2f(v01a[c]) + w10*bf2f(v10a[c]) + w11*bf2f(v11a[c]);
        vv[c+8] = w00*bf2f(v00b[c]) + w01*bf2f(v01b[c]) + w10*bf2f(v10b[c]) + w11*bf2f(v11b[c]);
      }
      u16* krow = &sm.a.ksmp[s_slot][hf << 4];
      uint2 q0 = {cvtpk(kk[0],kk[1]),   cvtpk(kk[2],kk[3])};
      uint2 q1 = {cvtpk(kk[4],kk[5]),   cvtpk(kk[6],kk[7])};
      uint2 q2 = {cvtpk(kk[8],kk[9]),   cvtpk(kk[10],kk[11])};
      uint2 q3 = {cvtpk(kk[12],kk[13]), cvtpk(kk[14],kk[15])};
      *(uint2*)(krow)      = q0;
      *(uint2*)(krow + 4)  = q1;
      *(uint2*)(krow + 8)  = q2;
      *(uint2*)(krow + 12) = q3;
#pragma unroll
      for (int j = 0; j < 16; j += 2) {
        uint32_t p = cvtpk(vv[j], vv[j+1]);
        sm.a.vT[(hf << 4) + j][s_slot]     = (u16)p;
        sm.a.vT[(hf << 4) + j + 1][s_slot] = (u16)(p >> 16);
      }
    }
    __syncthreads();   // S: ksmp, vT ready

    // ---- logits[q=16w2+4g+i][s=16nt+l15] (duplicated across v-groups) ----
    bf16x8 aq = ld_frag_g(qsPad + (size_t)((h << 6) + (w2 << 4) + l15)*32 + (g << 3));
    f32x4 lac[13];
#pragma unroll
    for (int nt = 0; nt < 13; ++nt) {
      bf16x8 bk = ld_frag(&sm.a.ksmp[(nt << 4) + l15][g << 3]);
      f32x4 z = (f32x4){0.f,0.f,0.f,0.f};
      lac[nt] = MFMA(aq, bk, z);
    }
    if (l15 >= 4) {      // mask s >= 196 (kills garbage from unwritten ksmp rows)
#pragma unroll
      for (int i = 0; i < 4; ++i) lac[12][i] = -1e30f;
    }
    // ---- softmax over s ----
    float srow[4];
#pragma unroll
    for (int i = 0; i < 4; ++i) {
      float m = lac[0][i];
#pragma unroll
      for (int nt = 1; nt < 13; ++nt) m = fmaxf(m, lac[nt][i]);
#pragma unroll
      for (int off = 1; off < 16; off <<= 1) m = fmaxf(m, __shfl_xor(m, off, 64));
      float sumv = 0.f;
#pragma unroll
      for (int nt = 0; nt < 13; ++nt) {
        float p = __expf(lac[nt][i] - m);
        lac[nt][i] = p; sumv += p;
      }
#pragma unroll
      for (int off = 1; off < 16; off <<= 1) sumv += __shfl_xor(sumv, off, 64);
      srow[i] = 1.0f / sumv;
    }
    // attn writes: v-groups write identical bits (benign); reader wave wrote its own rows
#pragma unroll
    for (int nt = 0; nt < 13; ++nt)
#pragma unroll
      for (int i = 0; i < 4; ++i)
        sm.a.attn[(w2 << 4) + (g << 2) + i][(nt << 4) + l15] = f2bf(lac[nt][i]*srow[i]);

    // ---- PV: o_h = attn @ v ----
    f32x4 o0 = (f32x4){0.f,0.f,0.f,0.f}, o1 = (f32x4){0.f,0.f,0.f,0.f};
#pragma unroll
    for (int kt = 0; kt < 7; ++kt) {
      bf16x8 ap = ld_frag(&sm.a.attn[(w2 << 4) + l15][(kt << 5) + (g << 3)]);
      bf16x8 b0 = ld_frag(&sm.a.vT[l15][(kt << 5) + (g << 3)]);
      bf16x8 b1 = ld_frag(&sm.a.vT[16 + l15][(kt << 5) + (g << 3)]);
      o0 = MFMA(ap, b0, o0);
      o1 = MFMA(ap, b1, o1);
    }
    // bias (bv commutes through softmax) + redistribute to A-frag layout (wave-local)
    float bv0 = bv[(h << 5) + l15];
    float bv1 = bv[(h << 5) + 16 + l15];
#pragma unroll
    for (int i = 0; i < 4; ++i) {
      sm.a.ore[(w2 << 4) + (g << 2) + i][l15]      = f2bf(o0[i] + bv0);
      sm.a.ore[(w2 << 4) + (g << 2) + i][16 + l15] = f2bf(o1[i] + bv1);
    }
    // ---- out-projection: v-group takes its 8 n-tiles ----
    bf16x8 ao = ld_frag(&sm.a.ore[(w2 << 4) + l15][g << 3]);
#pragma unroll
    for (int j = 0; j < 8; ++j) {
      int nt = (v << 3) + j;
      bf16x8 bo = ld_frag_g(Woutbf + (size_t)((nt << 4) + l15)*256 + (h << 5) + (g << 3));
      attacc[j] = MFMA(ao, bo, attacc[j]);
    }
  } // heads

  // ---- Phase C ----
  __syncthreads();   // all A-region reads done before aliasing ast/pos
#pragma unroll
  for (int j = 0; j < 8; ++j) {
    int nt = (v << 3) + j;
    float bo = bout[(nt << 4) + l15];
#pragma unroll
    for (int i = 0; i < 4; ++i) {
      int r = (w2 << 4) + (g << 2) + i;
      if (r < NQ) sm.c.ast[r][(nt << 4) + l15] = f2bf(attacc[j][i] + bo);
    }
  }
  // pos via 3x3 separable stencil [hy,1,ly](x)[hx,1,lx]/4 gathered from fT
  {
    float wy[3] = {hy, 1.0f, ly};
    float wx[3] = {hx, 1.0f, lx};
    for (int it = 0; it < 4; ++it) {
      int item = tid + (it << 9);
      if (item < NQ*32) {
        int q = item >> 5, c8 = (item & 31) << 3;
        int oy = q/7, ox = q - oy*7;
        float a[8] = {0.f,0.f,0.f,0.f,0.f,0.f,0.f,0.f};
#pragma unroll
        for (int j = 0; j < 3; ++j) {
          int ry = min(iy0 + (oy << 1) + j, FH - 1);
#pragma unroll
          for (int i = 0; i < 3; ++i) {
            int rx = min(ix0 + (ox << 1) + i, FW - 1);
            const u16* pt = fT + (((size_t)(ry*FW + rx)) << 8) + c8;
            us8 tv = *(const us8*)pt;
            float wji = wy[j]*wx[i];
#pragma unroll
            for (int c = 0; c < 8; ++c) a[c] += wji*bf2f(tv[c]);
          }
        }
        uint2 r0 = {cvtpk(0.25f*a[0], 0.25f*a[1]), cvtpk(0.25f*a[2], 0.25f*a[3])};
        uint2 r1 = {cvtpk(0.25f*a[4], 0.25f*a[5]), cvtpk(0.25f*a[6], 0.25f*a[7])};
        *(uint2*)(&sm.c.pos[q][c8])     = r0;
        *(uint2*)(&sm.c.pos[q][c8 + 4]) = r1;
      }
    }
  }
  __syncthreads();
  float ibal = 1.0f - bal;
  float* outp = out + (size_t)n*(E_DIM*NQ);
  for (int j = 0; j < 25; ++j) {
    int idx = (j << 9) + tid;
    if (idx < E_DIM*NQ) {
      int eo = idx/49;
      int q  = idx - eo*49;
      outp[idx] = bal*bf2f(sm.c.pos[q][eo]) + ibal*bf2f(sm.c.ast[q][eo]);
    }
  }
}

// ---------------- launcher ----------------
// ws: fT | fK | fV (19,922,944 B each) | Wk | Wv | Wo (131,072 each) | qs 32,768
extern "C" void kernel_launch(void* const* d_in, const int* in_sizes, int n_in,
                              void* d_out, int out_size, void* d_ws, size_t ws_size,
                              hipStream_t stream) {
  const float* features = (const float*)d_in[0];
  const float* rois     = (const float*)d_in[1];
  const float* cq       = (const float*)d_in[2];
  const float* ipw      = (const float*)d_in[3];
  const float* ipb      = (const float*)d_in[4];
  const float* opw      = (const float*)d_in[5];
  const float* opb      = (const float*)d_in[6];
  const float* balp     = (const float*)d_in[7];
  float* out = (float*)d_out;

  char* ws = (char*)d_ws;
  const size_t FMB = (size_t)HW_TOT*256*2;   // 19,922,944
  u16* fT = (u16*)ws;
  u16* fK = (u16*)(ws + FMB);
  u16* fV = (u16*)(ws + 2*FMB);
  u16* Wk = (u16*)(ws + 3*FMB);
  u16* Wv = Wk + 65536;
  u16* Wo = Wv + 65536;
  u16* qs = Wo + 65536;

  hipLaunchKernelGGL(prep_small, dim3(264), dim3(256), 0, stream,
                     ipw, opw, ipb, cq, Wk, Wv, Wo, qs);
  hipLaunchKernelGGL(proj_kv,    dim3(HW_TOT/64), dim3(512), 0, stream,
                     features, Wk, Wv, fT, fK, fV);
  hipLaunchKernelGGL(fused_roi_attn, dim3(NROIS), dim3(512), 0, stream,
                     rois, balp, ipb + 512, opb, fT, fK, fV, Wo, qs, out);
}